// Round 7
// baseline (761.056 us; speedup 1.0000x reference)
//
#include <hip/hip_runtime.h>

// ---------- common helpers ----------
typedef __attribute__((ext_vector_type(8))) short bf16x8;
typedef __attribute__((ext_vector_type(4))) float f32x4;

__device__ __forceinline__ short f2bf(float f){
  union { float f; unsigned u; } v; v.f = f;
  unsigned r = v.u + 0x7fffu + ((v.u >> 16) & 1u);   // RNE
  return (short)(r >> 16);
}
__device__ __forceinline__ bf16x8 pack8(float4 a, float4 b){
  bf16x8 v;
  v[0]=f2bf(a.x); v[1]=f2bf(a.y); v[2]=f2bf(a.z); v[3]=f2bf(a.w);
  v[4]=f2bf(b.x); v[5]=f2bf(b.y); v[6]=f2bf(b.z); v[7]=f2bf(b.w);
  return v;
}
__device__ __forceinline__ f32x4 mfma16(bf16x8 a, bf16x8 b, f32x4 c){
  return __builtin_amdgcn_mfma_f32_16x16x32_bf16(a, b, c, 0, 0, 0);
}
__device__ __forceinline__ float sigm(float x){
  return __builtin_amdgcn_rcpf(1.f + __expf(-x));
}
__device__ __forceinline__ float tanh_(float x){
  return 1.f - 2.f*__builtin_amdgcn_rcpf(1.f + __expf(2.f*x));
}

// ---------- 1) embedding + LSTM (final h) ---------- (unchanged)
__global__ __launch_bounds__(512,2) void lstm_kernel(
    const int* __restrict__ tokens, const float* __restrict__ embed,
    const float* __restrict__ Wih, const float* __restrict__ Whh,
    const float* __restrict__ bih, const float* __restrict__ bhh,
    float* __restrict__ feat)
{
  __shared__ short hbuf[2*32*128];   // 16 KB, XOR-swizzled rows of 256B
  __shared__ short xbuf[2*32*128];   // 16 KB, same layout
  __shared__ int   tokbuf[32*32];    // 4 KB
  const int tid  = threadIdx.x;
  const int wave = tid >> 6, lane = tid & 63;
  const int l15  = lane & 15, lhi = lane >> 4;
  const int nbase = blockIdx.x * 32;
  const int ucol  = wave*16 + l15;

  bf16x8 wihf[4][4], whhf[4][4];
  #pragma unroll
  for(int g=0; g<4; ++g){
    const float* wi = Wih + (size_t)(g*128 + ucol)*128;
    const float* wh = Whh + (size_t)(g*128 + ucol)*128;
    #pragma unroll
    for(int kt=0; kt<4; ++kt){
      int e0 = kt*32 + lhi*8;
      float4 a0 = *(const float4*)(wi+e0), a1 = *(const float4*)(wi+e0+4);
      float4 b0 = *(const float4*)(wh+e0), b1 = *(const float4*)(wh+e0+4);
      wihf[g][kt] = pack8(a0,a1);
      whhf[g][kt] = pack8(b0,b1);
    }
  }
  float bs[4];
  #pragma unroll
  for(int g=0; g<4; ++g) bs[g] = bih[g*128+ucol] + bhh[g*128+ucol];

  for(int i=tid; i<1024; i+=512) tokbuf[i] = tokens[(size_t)nbase*32 + i];

  float c[2][4], hreg[2][4];
  #pragma unroll
  for(int m=0;m<2;++m) for(int r=0;r<4;++r){ c[m][r]=0.f; hreg[m][r]=0.f; }

  *(bf16x8*)((char*)hbuf + tid*16) = (bf16x8){0,0,0,0,0,0,0,0};
  __syncthreads();

  const int srow = tid >> 4, sseg = tid & 15;
  {
    int tok = tokbuf[srow*32 + 0];
    const float* e = embed + (size_t)tok*128 + sseg*8;
    float4 a = *(const float4*)e, b = *(const float4*)(e+4);
    int byte = (srow*256 + sseg*16) ^ ((srow&7)<<4);
    *(bf16x8*)((char*)xbuf + byte) = pack8(a,b);
  }
  __syncthreads();

  float4 sa, sb;
  #pragma unroll 1
  for(int l=0; l<32; ++l){
    if(l < 31){
      int tok = tokbuf[srow*32 + l + 1];
      const float* e = embed + (size_t)tok*128 + sseg*8;
      sa = *(const float4*)e; sb = *(const float4*)(e+4);
    }
    const char* hb = (const char*)hbuf + (l&1)*8192;
    const char* xb = (const char*)xbuf + (l&1)*8192;
    f32x4 acc[2][4];
    #pragma unroll
    for(int m=0;m<2;++m) for(int g=0;g<4;++g) acc[m][g]=(f32x4){0.f,0.f,0.f,0.f};
    #pragma unroll
    for(int kt=0; kt<4; ++kt){
      int cbyte = kt*64 + lhi*16;
      int swz = (l15&7)<<4;
      int a0 = (l15*256 + cbyte) ^ swz;
      int a1 = ((16+l15)*256 + cbyte) ^ swz;
      bf16x8 h0 = *(const bf16x8*)(hb + a0);
      bf16x8 h1 = *(const bf16x8*)(hb + a1);
      bf16x8 x0 = *(const bf16x8*)(xb + a0);
      bf16x8 x1 = *(const bf16x8*)(xb + a1);
      #pragma unroll
      for(int g=0; g<4; ++g){
        acc[0][g]=mfma16(h0, whhf[g][kt], acc[0][g]);
        acc[1][g]=mfma16(h1, whhf[g][kt], acc[1][g]);
        acc[0][g]=mfma16(x0, wihf[g][kt], acc[0][g]);
        acc[1][g]=mfma16(x1, wihf[g][kt], acc[1][g]);
      }
    }
    char* hn = (char*)hbuf + ((l+1)&1)*8192;
    #pragma unroll
    for(int m=0;m<2;++m){
      #pragma unroll
      for(int r=0;r<4;++r){
        float gi = acc[m][0][r] + bs[0];
        float gf = acc[m][1][r] + bs[1];
        float gg = acc[m][2][r] + bs[2];
        float go = acc[m][3][r] + bs[3];
        float i_ = sigm(gi), f_ = sigm(gf), o_ = sigm(go), g_ = tanh_(gg);
        float cc = f_*c[m][r] + i_*g_;
        c[m][r] = cc;
        float hh = o_*tanh_(cc);
        hreg[m][r] = hh;
        int row = m*16 + lhi*4 + r;
        int wb = (row*256 + ucol*2) ^ ((row&7)<<4);
        *(short*)(hn + wb) = f2bf(hh);
      }
    }
    if(l < 31){
      int byte = ((l+1)&1)*8192 + ((srow*256 + sseg*16) ^ ((srow&7)<<4));
      *(bf16x8*)((char*)xbuf + byte) = pack8(sa,sb);
    }
    __syncthreads();
  }
  #pragma unroll
  for(int m=0;m<2;++m) for(int r=0;r<4;++r){
    int row = nbase + m*16 + lhi*4 + r;
    feat[(size_t)row*128 + ucol] = hreg[m][r];
  }
}

// ---------- 2) Y1b[k>>3][j][k&7] = (feat @ gc1_W)[k][j], bf16 ----------
// Blocked K-major layout: element (j,k) at Y1b[k*256 + j*8] for k%8==0 base.
// r7: layout changed from [j][k] (16KB row stride -> 64 cache lines per
// gemm1 B-load instr) to k-chunk-blocked (contiguous 256B per 16 lanes).
__global__ __launch_bounds__(256) void gc1_kernel(
  const float* __restrict__ feat, const float* __restrict__ W1,
  short* __restrict__ Y1b)
{
  __shared__ float fs[128][36];
  int tid = threadIdx.x; int nb = blockIdx.x*32;
  #pragma unroll
  for(int i=0;i<4;++i){
    int idx = i*256 + tid;
    float4 v = ((const float4*)(feat + (size_t)nb*128))[idx];
    int n = idx>>5, k0 = (idx&31)*4;
    fs[k0][n]=v.x; fs[k0+1][n]=v.y; fs[k0+2][n]=v.z; fs[k0+3][n]=v.w;
  }
  __syncthreads();
  float acc[32];
  #pragma unroll
  for(int n=0;n<32;++n) acc[n]=0.f;
  int j = tid;
  for(int k=0;k<128;++k){
    float w = W1[k*256 + j];
    #pragma unroll
    for(int n4=0;n4<8;++n4){
      float4 f = *(const float4*)&fs[k][n4*4];
      acc[n4*4+0]+=f.x*w; acc[n4*4+1]+=f.y*w; acc[n4*4+2]+=f.z*w; acc[n4*4+3]+=f.w*w;
    }
  }
  // store 4 chunks of 8 consecutive-k bf16 at [(nb/8+c)*2048 + j*8]
  #pragma unroll
  for(int c=0;c<4;++c){
    bf16x8 v = pack8(*(const float4*)&acc[c*8], *(const float4*)&acc[c*8+4]);
    *(bf16x8*)(Y1b + ((size_t)(nb>>3) + c)*2048 + j*8) = v;
  }
}

// ---------- 3) part[ks] = adj @ Y1 slice (bf16 MFMA, split-K=4) ----------
// r7: B reads from blocked Y1b (contiguous 256B/16-lane segment, 8x fewer
// L2 transactions than r4's 16KB-stride scatter) + single barrier per
// K-step (dbuf needs only one; r4 had two full drains/step).
__global__ __launch_bounds__(256,2) void gemm1_kernel(
  const float* __restrict__ adj, const short* __restrict__ Y1b,
  float* __restrict__ part)
{
  __shared__ short As[2*64*128];     // 32 KB
  int tid=threadIdx.x, lane=tid&63, wid=tid>>6;
  int wr=wid>>1, wc=wid&1, l15=lane&15, lhi=lane>>4;
  int rb=(blockIdx.x>>2)*64;
  int ks=blockIdx.x&3;
  size_t kb0=(size_t)ks*2048;
  f32x4 acc[2][8];
  #pragma unroll
  for(int m=0;m<2;++m) for(int n=0;n<8;++n) acc[m][n]=(f32x4){0.f,0.f,0.f,0.f};

  const int srow = tid>>2, sseg = tid&3;           // stage 32 floats/thread
  const float* asrc = adj + (size_t)(rb+srow)*8192 + kb0 + sseg*32;
  float4 r[8];
  {
    const float4* p = (const float4*)asrc;
    #pragma unroll
    for(int i=0;i<8;++i) r[i]=p[i];
  }
  #pragma unroll 1
  for(int t=0; t<16; ++t){
    // write staged regs -> As[t&1] (last read of this buffer was t-2;
    // barriers at t-1 and t separate -> single barrier per step is safe)
    char* dst = (char*)As + (t&1)*16384;
    #pragma unroll
    for(int q=0;q<4;++q){
      int byte = (srow*256 + (sseg*32+q*8)*2) ^ ((srow&7)<<4);
      *(bf16x8*)(dst + byte) = pack8(r[2*q], r[2*q+1]);
    }
    __syncthreads();
    // issue next A loads early (hide HBM latency under compute)
    if(t<15){
      const float4* p = (const float4*)(asrc + (t+1)*128);
      #pragma unroll
      for(int i=0;i<8;++i) r[i]=p[i];
    }
    const char* cur = (const char*)As + (t&1)*16384;
    #pragma unroll
    for(int kk=0;kk<4;++kk){
      bf16x8 af[2];
      #pragma unroll
      for(int m=0;m<2;++m){
        int row = wr*32 + m*16 + l15;
        int byte = (row*256 + (kk*32+lhi*8)*2) ^ ((row&7)<<4);
        af[m] = *(const bf16x8*)(cur + byte);
      }
      // blocked B: element (j,k) at Y1b[k*256 + j*8]
      const short* yb = Y1b + (size_t)(kb0 + t*128 + kk*32 + lhi*8)*256;
      #pragma unroll
      for(int n=0;n<8;++n){
        bf16x8 bfr = *(const bf16x8*)(yb + (wc*128 + n*16 + l15)*8);
        #pragma unroll
        for(int m=0;m<2;++m) acc[m][n]=mfma16(af[m], bfr, acc[m][n]);
      }
    }
  }
  float* pb = part + ((size_t)ks*8192 + rb)*256;
  #pragma unroll
  for(int m=0;m<2;++m) for(int n=0;n<8;++n){
    int row0=wr*32+m*16+lhi*4, col=wc*128+n*16+l15;
    #pragma unroll
    for(int q=0;q<4;++q) pb[(size_t)(row0+q)*256+col]=acc[m][n][q];
  }
}

// ---------- 4) h1 = relu(sum_k part + b1); Y2t = (h1 @ gc2_W)^T ---------- (unchanged)
__global__ __launch_bounds__(256) void reduce_kernel(
  const float* __restrict__ part, const float* __restrict__ b1,
  const float* __restrict__ W2, float* __restrict__ Y2t)
{
  __shared__ float h1s[8][256];
  __shared__ float w2s[256*16];
  int tid=threadIdx.x, rb=blockIdx.x*8;
  for(int i=tid;i<1024;i+=256) ((float4*)w2s)[i]=((const float4*)W2)[i];
  int r=tid>>5, cb=(tid&31)*8;
  const float* p0 = part + (size_t)(rb+r)*256 + cb;
  float a[8];
  #pragma unroll
  for(int q=0;q<8;++q) a[q]=0.f;
  #pragma unroll
  for(int ks=0;ks<4;++ks){
    const float* p = p0 + (size_t)ks*2097152;
    float4 u=((const float4*)p)[0], v=((const float4*)p)[1];
    a[0]+=u.x; a[1]+=u.y; a[2]+=u.z; a[3]+=u.w;
    a[4]+=v.x; a[5]+=v.y; a[6]+=v.z; a[7]+=v.w;
  }
  #pragma unroll
  for(int q=0;q<8;++q){
    float v = a[q] + b1[cb+q];
    h1s[r][cb+q] = v>0.f ? v : 0.f;
  }
  __syncthreads();
  if(tid<128){
    int rr=tid>>4, j=tid&15;
    float s=0.f;
    for(int k4=0;k4<64;++k4){
      float4 h = *(const float4*)&h1s[rr][k4*4];
      s += h.x*w2s[(k4*4+0)*16+j] + h.y*w2s[(k4*4+1)*16+j]
         + h.z*w2s[(k4*4+2)*16+j] + h.w*w2s[(k4*4+3)*16+j];
    }
    Y2t[(size_t)j*8192 + rb + rr] = s;    // transposed for gemm2 coalescing
  }
}

// ---------- 5) out = log_softmax(adj @ Y2 + b2), Y2 transposed ---------- (unchanged)
__global__ __launch_bounds__(256,2) void gemm2_kernel(
  const float* __restrict__ adj, const float* __restrict__ Y2t,
  const float* __restrict__ b2, float* __restrict__ out)
{
  __shared__ float red[16][16];
  int tid=threadIdx.x, lane=tid&63, w=tid>>6;
  int rb=blockIdx.x*16;
  int rowb=rb + w*4;
  float acc[4][16];
  #pragma unroll
  for(int rr=0;rr<4;++rr) for(int j=0;j<16;++j) acc[rr][j]=0.f;
  const float* a0 = adj + (size_t)rowb*8192;
  float4 av[4];
  #pragma unroll
  for(int rr=0;rr<4;++rr) av[rr] = *(const float4*)(a0 + (size_t)rr*8192 + lane*4);
  #pragma unroll 1
  for(int it=0; it<32; ++it){
    float4 nv[4];
    if(it<31){
      int kbn = (it+1)*256 + lane*4;
      #pragma unroll
      for(int rr=0;rr<4;++rr) nv[rr] = *(const float4*)(a0 + (size_t)rr*8192 + kbn);
    }
    int kb = it*256 + lane*4;
    #pragma unroll
    for(int j=0;j<16;++j){
      float4 y = *(const float4*)(Y2t + (size_t)j*8192 + kb);
      #pragma unroll
      for(int rr=0;rr<4;++rr)
        acc[rr][j] += av[rr].x*y.x + av[rr].y*y.y + av[rr].z*y.z + av[rr].w*y.w;
    }
    #pragma unroll
    for(int rr=0;rr<4;++rr) av[rr]=nv[rr];
  }
  #pragma unroll
  for(int mask=32; mask; mask>>=1){
    #pragma unroll
    for(int rr=0;rr<4;++rr)
      #pragma unroll
      for(int j=0;j<16;++j)
        acc[rr][j] += __shfl_xor(acc[rr][j], mask);
  }
  if(lane==0){
    #pragma unroll
    for(int rr=0;rr<4;++rr)
      #pragma unroll
      for(int j=0;j<16;++j) red[w*4+rr][j]=acc[rr][j];
  }
  __syncthreads();
  int r2=tid>>4, j=tid&15;
  float logit = red[r2][j] + b2[j];
  float m = logit;
  for(int msk=8;msk;msk>>=1) m = fmaxf(m, __shfl_xor(m, msk, 16));
  float e = __expf(logit - m);
  float den = e;
  for(int msk=8;msk;msk>>=1) den += __shfl_xor(den, msk, 16);
  out[(size_t)(rb+r2)*16 + j] = logit - m - __logf(den);
}

// ---------- launch ----------
extern "C" void kernel_launch(void* const* d_in, const int* in_sizes, int n_in,
                              void* d_out, int out_size, void* d_ws, size_t ws_size,
                              hipStream_t stream) {
  const int*   tokens = (const int*)d_in[0];
  const float* adj    = (const float*)d_in[1];
  const float* embed  = (const float*)d_in[2];
  const float* Wih    = (const float*)d_in[3];
  const float* Whh    = (const float*)d_in[4];
  const float* bih    = (const float*)d_in[5];
  const float* bhh    = (const float*)d_in[6];
  const float* W1     = (const float*)d_in[7];
  const float* b1     = (const float*)d_in[8];
  const float* W2     = (const float*)d_in[9];
  const float* b2     = (const float*)d_in[10];
  float* out = (float*)d_out;

  char* ws = (char*)d_ws;
  float* feat = (float*)ws;                       // 4 MB
  short* Y1b  = (short*)(ws + (4u<<20));          // 4 MB  (bf16 blocked [1024][256][8])
  float* part = (float*)(ws + (8u<<20));          // 32 MB (4 x [8192][256] f32)
  float* Y2t  = (float*)(ws + (40u<<20));         // 0.5 MB ([16][8192] f32)

  lstm_kernel  <<<dim3(256),  dim3(512), 0, stream>>>(tokens, embed, Wih, Whh, bih, bhh, feat);
  gc1_kernel   <<<dim3(256),  dim3(256), 0, stream>>>(feat, W1, Y1b);
  gemm1_kernel <<<dim3(512),  dim3(256), 0, stream>>>(adj, Y1b, part);
  reduce_kernel<<<dim3(1024), dim3(256), 0, stream>>>(part, b1, W2, Y2t);
  gemm2_kernel <<<dim3(512),  dim3(256), 0, stream>>>(adj, Y2t, b2, out);
}